// Round 21
// baseline (141.694 us; speedup 1.0000x reference)
//
#include <hip/hip_runtime.h>
#include <hip/hip_bf16.h>
#include <math.h>

#define NF 128
#define NP 256

typedef __attribute__((ext_vector_type(8))) short bf16x8;
typedef __attribute__((ext_vector_type(4))) short bf16x4;
typedef __attribute__((ext_vector_type(4))) float f32x4;

#define GLOBAL_AS __attribute__((address_space(1)))
#define LDS_AS __attribute__((address_space(3)))

// ---------------- ONE prepack kernel: wp1 | wp2 | wp3 | fwt | tpack(ew1,ew2,ew3) ----------------
__device__ __forceinline__ void tpack_tile(const float* __restrict__ src,
                                           __hip_bfloat16* __restrict__ dst,
                                           int P, int Q, int pt, int qt,
                                           int tid, float (*t)[33])
{
    const int rr = tid >> 5, c = tid & 31;
    #pragma unroll
    for (int i = 0; i < 4; ++i)
        t[rr + i * 8][c] = src[(size_t)(pt * 32 + rr + i * 8) * Q + qt * 32 + c];
    __syncthreads();
    #pragma unroll
    for (int i = 0; i < 4; ++i)
        dst[(size_t)(qt * 32 + rr + i * 8) * P + pt * 32 + c] =
            __float2bfloat16(t[c][rr + i * 8]);
}

__global__ void __launch_bounds__(256) packs_k(
    const float* __restrict__ cw1, const float* __restrict__ cw2,
    const float* __restrict__ cw3, const float* __restrict__ fw,
    const float* __restrict__ ew1, const float* __restrict__ ew2,
    const float* __restrict__ ew3,
    __hip_bfloat16* __restrict__ wp1, __hip_bfloat16* __restrict__ wp2,
    __hip_bfloat16* __restrict__ wp3, float* __restrict__ fwt,
    __hip_bfloat16* __restrict__ ew1b, __hip_bfloat16* __restrict__ ew2b,
    __hip_bfloat16* __restrict__ ew3b)
{
    __shared__ float t[32][33];
    const int bid = blockIdx.x, tid = threadIdx.x;
    if (bid < 8) {
        int i = bid * 256 + tid;
        if (i >= 2048) return;
        int s = i >> 10, co = (i >> 5) & 31, k = i & 31;
        int o = s * 8 + (k >> 2), ch = k & 3;
        float v = 0.f;
        if (o < 9 && ch < 3) v = cw1[(size_t)(co * 3 + ch) * 9 + o];
        wp1[i] = __float2bfloat16(v);
    } else if (bid < 80) {
        int i = (bid - 8) * 256 + tid;
        if (i >= 9 * 64 * 32) return;
        int o = i / 2048, r = i - o * 2048;
        int co = r >> 5, ci = r & 31;
        wp2[i] = __float2bfloat16(cw2[(size_t)(co * 32 + ci) * 9 + o]);
    } else if (bid < 368) {
        int i = (bid - 80) * 256 + tid;
        if (i >= 9 * 128 * 64) return;
        int o = i / 8192, r = i - o * 8192;
        int co = r >> 6, ci = r & 63;
        wp3[i] = __float2bfloat16(cw3[(size_t)(co * 64 + ci) * 9 + o]);
    } else if (bid < 1216) {
        int i = (bid - 368) * 256 + tid;
        if (i >= 53 * 4096) return;
        int o = i >> 12, k = i & 4095;
        fwt[i] = fw[(size_t)k * 53 + o];
    } else if (bid < 9408) {
        int r = bid - 1216;
        int f = r >> 6, tile = r & 63;
        tpack_tile(ew1 + (size_t)f * 65536, ew1b + (size_t)f * 65536,
                   256, 256, tile >> 3, tile & 7, tid, t);
    } else if (bid < 13504) {
        int r = bid - 9408;
        int f = r >> 5, tile = r & 31;
        tpack_tile(ew2 + (size_t)f * 32768, ew2b + (size_t)f * 32768,
                   256, 128, tile >> 2, tile & 3, tid, t);
    } else {
        int r = bid - 13504;
        int f = r >> 2, tile = r & 3;
        tpack_tile(ew3 + (size_t)f * 4096, ew3b + (size_t)f * 4096,
                   128, 32, tile, 0, tid, t);
    }
}

// ---------------- conv1 via MFMA, 512 threads: waves = (row-pair rp, co-half coh) ----------------
__global__ void __launch_bounds__(512, 2) conv1_mfma(
    const float* __restrict__ x,
    const __hip_bfloat16* __restrict__ wp1,
    const float* __restrict__ bias,
    __hip_bfloat16* __restrict__ out)
{
    __shared__ char lds[14 * 130 * 8];
    const int rb  = blockIdx.x * 8;
    const int b   = blockIdx.z;
    const int tid = threadIdx.x;

    #pragma unroll
    for (int t = 0; t < 4; ++t) {
        int u = tid + t * 512;
        if (u < 14 * 130) {
            int px = u % 130, row = u / 130;
            int gy = rb + row - 1, gx = px - 1;
            unsigned short hv[4] = {0, 0, 0, 0};
            if (gy >= 0 && gy < 128 && gx >= 0 && gx < 128) {
                size_t base = (((size_t)b * 3) * 128 + gy) * 128 + gx;
                __hip_bfloat16 h0 = __float2bfloat16(x[base]);
                __hip_bfloat16 h1 = __float2bfloat16(x[base + 16384]);
                __hip_bfloat16 h2 = __float2bfloat16(x[base + 32768]);
                __builtin_memcpy(&hv[0], &h0, 2);
                __builtin_memcpy(&hv[1], &h1, 2);
                __builtin_memcpy(&hv[2], &h2, 2);
            }
            *(int2*)(lds + u * 8) = *(const int2*)hv;
        }
    }
    __syncthreads();

    const int w = tid >> 6, lane = tid & 63, p = lane & 15, q = lane >> 4;
    const int rp = w & 3, coh = w >> 2;

    f32x4 acc[16];
    #pragma unroll
    for (int m = 0; m < 16; ++m) {
        acc[m][0] = 0.f; acc[m][1] = 0.f; acc[m][2] = 0.f; acc[m][3] = 0.f;
    }

    #pragma unroll
    for (int s = 0; s < 2; ++s) {
        bf16x8 bfr = *(const bf16x8*)(wp1 + (size_t)(s * 32 + coh * 16 + p) * 32 + q * 8);
        const int o0 = s * 8 + q * 2, o1 = o0 + 1;
        const int dy0 = o0 / 3, dx0 = o0 - 3 * dy0;
        const int dy1 = o1 / 3, dx1 = o1 - 3 * dy1;
        #pragma unroll
        for (int m = 0; m < 16; ++m) {
            const int mr = m >> 3, mx = m & 7;
            const int r0 = (2 * rp + mr + dy0) * 130 + mx * 16 + p + dx0;
            const int r1 = (2 * rp + mr + dy1) * 130 + mx * 16 + p + dx1;
            bf16x4 lo = *(const bf16x4*)(lds + r0 * 8);
            bf16x4 hi = *(const bf16x4*)(lds + r1 * 8);
            bf16x8 afr = __builtin_shufflevector(lo, hi, 0, 1, 2, 3, 4, 5, 6, 7);
            acc[m] = __builtin_amdgcn_mfma_f32_16x16x32_bf16(afr, bfr, acc[m], 0, 0, 0);
        }
    }

    const int prow = (rb >> 1) + rp;
    const float bv = bias[coh * 16 + p];
    #pragma unroll
    for (int mx = 0; mx < 8; ++mx) {
        f32x4 lo = acc[mx], hi = acc[8 + mx];
        float v0 = fmaxf(fmaxf(fmaxf(lo[0], lo[1]), fmaxf(hi[0], hi[1])) + bv, 0.f);
        float v1 = fmaxf(fmaxf(fmaxf(lo[2], lo[3]), fmaxf(hi[2], hi[3])) + bv, 0.f);
        int px = mx * 8 + q * 2;
        size_t base = ((size_t)(b * 64 + prow) * 64 + px) * 32 + coh * 16 + p;
        out[base]      = __float2bfloat16(v0);
        out[base + 32] = __float2bfloat16(v1);
    }
}

// ---------------- MFMA conv3x3 + ReLU + maxpool2 (512 thr; SWZ mask = CH-1, both sides) ----------------
template<int W, int CIN, int COUT, int SWZ, int OUTF>
__global__ void __launch_bounds__(512, 2) conv_mfma(
    const __hip_bfloat16* __restrict__ in,
    const __hip_bfloat16* __restrict__ wp,
    const float* __restrict__ bias,
    __hip_bfloat16* __restrict__ outb,
    float* __restrict__ outf)
{
    constexpr int XW  = W / 16;
    constexpr int AF  = 2 * XW;
    constexpr int BF  = COUT / 32;
    constexpr int CH  = CIN / 8;
    constexpr int CM  = CH - 1;          // swizzle mask (stays within ch range)
    constexpr int KH  = CIN / 32;
    constexpr int NSTEP = 9 * KH;
    constexpr int PXW = W + 2;
    constexpr int UNITS  = 10 * PXW * CH;
    constexpr int NIT    = (UNITS + 511) / 512;
    constexpr int STAGEB = UNITS * 16;
    constexpr int OUTLDS = OUTF ? (COUT * 68 * 4) : 0;
    constexpr int LDSB   = STAGEB > OUTLDS ? STAGEB : OUTLDS;

    __shared__ int4 ldsv[(LDSB + 15) / 16];
    char* ldsc = (char*)ldsv;

    const int rb  = blockIdx.x * 8;
    const int b   = blockIdx.z;
    const int tid = threadIdx.x;
    const int w = tid >> 6, lane = tid & 63, p = lane & 15, q = lane >> 4;
    const int rp = w & 3, coh = w >> 2;
    const int cb = coh * (COUT / 2);

    #pragma unroll
    for (int t = 0; t < NIT; ++t) {
        int u = tid + t * 512;
        if (u < UNITS) {
            int ch = u % CH; int pl = u / CH;
            int xx = pl % PXW; int row = pl / PXW;
            int gy = rb + row - 1, gx = xx - 1;
            if (gy >= 0 && gy < W && gx >= 0 && gx < W) {
                int ch_src = SWZ ? (ch ^ (pl & CM)) : ch;
                const __hip_bfloat16* gp = in + ((size_t)(b * W + gy) * W + gx) * CIN + ch_src * 8;
                char* lb = ldsc + (size_t)(t * 512 + (tid & ~63)) * 16;
                __builtin_amdgcn_global_load_lds(
                    (const GLOBAL_AS void*)gp, (LDS_AS void*)lb, 16, 0, 0);
            } else {
                *(int4*)(ldsc + (size_t)u * 16) = make_int4(0, 0, 0, 0);
            }
        }
    }

    bf16x8 bcur[BF], bnxt[BF];
    #pragma unroll
    for (int n = 0; n < BF; ++n)
        bcur[n] = *(const bf16x8*)(wp + (size_t)(cb + n * 16 + p) * CIN + q * 8);

    __syncthreads();

    f32x4 acc[AF][BF];
    #pragma unroll
    for (int m = 0; m < AF; ++m)
        #pragma unroll
        for (int n = 0; n < BF; ++n) {
            acc[m][n][0] = 0.f; acc[m][n][1] = 0.f;
            acc[m][n][2] = 0.f; acc[m][n][3] = 0.f;
        }

    float bv[BF];
    #pragma unroll
    for (int n = 0; n < BF; ++n) bv[n] = bias[cb + n * 16 + p];

    #pragma unroll 1
    for (int s = 0; s < NSTEP; ++s) {
        const int o  = (KH == 1) ? s : (s >> 1);
        const int h  = (KH == 1) ? 0 : (s & 1);
        const int ky = o / 3, kx = o - 3 * (o / 3);

        if (s + 1 < NSTEP) {
            const int o2 = (KH == 1) ? (s + 1) : ((s + 1) >> 1);
            const int h2 = (KH == 1) ? 0 : ((s + 1) & 1);
            #pragma unroll
            for (int n = 0; n < BF; ++n)
                bnxt[n] = *(const bf16x8*)(wp + (size_t)(o2 * COUT + cb + n * 16 + p) * CIN + h2 * 32 + q * 8);
        }

        bf16x8 afr[AF];
        #pragma unroll
        for (int m = 0; m < AF; ++m) {
            const int mr = m / XW, mx = m % XW;
            const int pix = (2 * rp + mr + ky) * PXW + mx * 16 + kx + p;
            const int ch = h * 4 + q;
            const int slot = SWZ ? (pix * CH + (ch ^ (pix & CM))) : (pix * CH + ch);
            afr[m] = *(const bf16x8*)(ldsc + slot * 16);
        }
        #pragma unroll
        for (int m = 0; m < AF; ++m)
            #pragma unroll
            for (int n = 0; n < BF; ++n)
                acc[m][n] = __builtin_amdgcn_mfma_f32_16x16x32_bf16(afr[m], bcur[n], acc[m][n], 0, 0, 0);

        #pragma unroll
        for (int n = 0; n < BF; ++n) bcur[n] = bnxt[n];
    }

    const int prow = (rb >> 1) + rp;
    if constexpr (OUTF == 0) {
        #pragma unroll
        for (int mx = 0; mx < XW; ++mx)
            #pragma unroll
            for (int n = 0; n < BF; ++n) {
                f32x4 lo = acc[mx][n], hi = acc[XW + mx][n];
                float v0 = fmaxf(fmaxf(fmaxf(lo[0], lo[1]), fmaxf(hi[0], hi[1])) + bv[n], 0.f);
                float v1 = fmaxf(fmaxf(fmaxf(lo[2], lo[3]), fmaxf(hi[2], hi[3])) + bv[n], 0.f);
                int px = mx * 8 + q * 2;
                size_t base = ((size_t)(b * (W / 2) + prow) * (W / 2) + px) * COUT + cb + n * 16 + p;
                outb[base]        = __float2bfloat16(v0);
                outb[base + COUT] = __float2bfloat16(v1);
            }
    } else {
        __syncthreads();
        float* fl = (float*)ldsc;
        #pragma unroll
        for (int mx = 0; mx < XW; ++mx)
            #pragma unroll
            for (int n = 0; n < BF; ++n) {
                f32x4 lo = acc[mx][n], hi = acc[XW + mx][n];
                float v0 = fmaxf(fmaxf(fmaxf(lo[0], lo[1]), fmaxf(hi[0], hi[1])) + bv[n], 0.f);
                float v1 = fmaxf(fmaxf(fmaxf(lo[2], lo[3]), fmaxf(hi[2], hi[3])) + bv[n], 0.f);
                int px = mx * 8 + q * 2;
                fl[(cb + n * 16 + p) * 68 + rp * 16 + px]     = v0;
                fl[(cb + n * 16 + p) * 68 + rp * 16 + px + 1] = v1;
            }
        __syncthreads();
        for (int i = tid; i < COUT * 16; i += 512) {
            int c = i >> 4, j4 = i & 15;
            float4 vv = *(const float4*)&fl[c * 68 + j4 * 4];
            *(float4*)(outf + (size_t)(b * COUT + c) * 256 + (rb >> 1) * 16 + j4 * 4) = vv;
        }
    }
}

// ---------------- experts via MFMA, 64-row blocks, fused attention (in-register) ----------------
__global__ void __launch_bounds__(256, 2) experts_mfma(
    const float* __restrict__ feat, const float* __restrict__ Wa,
    const float* __restrict__ ba,
    const __hip_bfloat16* __restrict__ w1, const float* __restrict__ eb1,
    const __hip_bfloat16* __restrict__ w2, const float* __restrict__ eb2,
    const __hip_bfloat16* __restrict__ w3, const float* __restrict__ eb3,
    float* __restrict__ z)
{
    const int f  = blockIdx.x;
    const int r0 = blockIdx.y * 64;
    const int tid = threadIdx.x;

    __shared__ __attribute__((aligned(16))) char lds[65536];
    char* Xb  = lds;
    char* H1b = lds + 32768;
    char* H2b = lds;

    #pragma unroll
    for (int t = 0; t < 8; ++t) {
        int u = tid + t * 256;
        int row = u >> 5, ch = u & 31;
        int b = r0 + row;
        const float* src = feat + ((size_t)b * NF + f) * NP + ch * 8;
        float4 v0 = *(const float4*)src;
        float4 v1 = *(const float4*)(src + 4);
        unsigned short hv[8];
        float vv[8] = {v0.x, v0.y, v0.z, v0.w, v1.x, v1.y, v1.z, v1.w};
        #pragma unroll
        for (int j = 0; j < 8; ++j) {
            __hip_bfloat16 hb = __float2bfloat16(vv[j]);
            __builtin_memcpy(&hv[j], &hb, 2);
        }
        int slot = row * 32 + (ch ^ (row & 7));
        *(int4*)(Xb + slot * 16) = *(const int4*)hv;
    }

    const int wv = tid >> 6, lane = tid & 63, p = lane & 15, q = lane >> 4;
    const int mrow = wv * 16;

    float att_val;
    {
        int rl = lane >> 2, sub = lane & 3;
        const float* fr = feat + ((size_t)(r0 + mrow + rl) * NF + f) * NP + sub * 64;
        const float* wr = Wa + (size_t)f * NP + sub * 64;
        float s = 0.f;
        #pragma unroll
        for (int j = 0; j < 64; j += 4) {
            float4 a  = *(const float4*)(fr + j);
            float4 w4 = *(const float4*)(wr + j);
            s += a.x * w4.x + a.y * w4.y + a.z * w4.z + a.w * w4.w;
        }
        s += __shfl_xor(s, 1);
        s += __shfl_xor(s, 2);
        att_val = 1.f / (1.f + expf(-(s + ba[f])));
    }
    __syncthreads();

    f32x4 acc1[16];
    #pragma unroll
    for (int n = 0; n < 16; ++n) { acc1[n][0]=0.f; acc1[n][1]=0.f; acc1[n][2]=0.f; acc1[n][3]=0.f; }
    #pragma unroll
    for (int k = 0; k < 8; ++k) {
        bf16x8 bfr[16];
        #pragma unroll
        for (int n = 0; n < 16; ++n)
            bfr[n] = *(const bf16x8*)(w1 + ((size_t)f * 256 + n * 16 + p) * 256 + k * 32 + q * 8);
        int row = mrow + p, ch = k * 4 + q;
        bf16x8 afr = *(const bf16x8*)(Xb + (row * 32 + (ch ^ (row & 7))) * 16);
        #pragma unroll
        for (int n = 0; n < 16; ++n)
            acc1[n] = __builtin_amdgcn_mfma_f32_16x16x32_bf16(afr, bfr[n], acc1[n], 0, 0, 0);
    }
    #pragma unroll
    for (int n = 0; n < 16; ++n) {
        int col = n * 16 + p;
        float bb = eb1[(size_t)f * 256 + col];
        #pragma unroll
        for (int reg = 0; reg < 4; ++reg) {
            int rowl = q * 4 + reg;
            float av = __shfl(att_val, rowl << 2);
            float v = fmaxf(av * acc1[n][reg] + bb, 0.f);
            int row = mrow + rowl;
            int slot = row * 32 + ((col >> 3) ^ (row & 7));
            *(__hip_bfloat16*)(H1b + slot * 16 + (col & 7) * 2) = __float2bfloat16(v);
        }
    }
    __syncthreads();

    f32x4 acc2[8];
    #pragma unroll
    for (int n = 0; n < 8; ++n) { acc2[n][0]=0.f; acc2[n][1]=0.f; acc2[n][2]=0.f; acc2[n][3]=0.f; }
    #pragma unroll
    for (int k = 0; k < 8; ++k) {
        bf16x8 bfr[8];
        #pragma unroll
        for (int n = 0; n < 8; ++n)
            bfr[n] = *(const bf16x8*)(w2 + ((size_t)f * 128 + n * 16 + p) * 256 + k * 32 + q * 8);
        int row = mrow + p, ch = k * 4 + q;
        bf16x8 afr = *(const bf16x8*)(H1b + (row * 32 + (ch ^ (row & 7))) * 16);
        #pragma unroll
        for (int n = 0; n < 8; ++n)
            acc2[n] = __builtin_amdgcn_mfma_f32_16x16x32_bf16(afr, bfr[n], acc2[n], 0, 0, 0);
    }
    #pragma unroll
    for (int n = 0; n < 8; ++n) {
        int col = n * 16 + p;
        float bb = eb2[(size_t)f * 128 + col];
        #pragma unroll
        for (int reg = 0; reg < 4; ++reg) {
            float v = fmaxf(acc2[n][reg] + bb, 0.f);
            int row = mrow + q * 4 + reg;
            int slot = row * 16 + ((col >> 3) ^ (row & 7));
            *(__hip_bfloat16*)(H2b + slot * 16 + (col & 7) * 2) = __float2bfloat16(v);
        }
    }
    __syncthreads();

    f32x4 acc3[2];
    #pragma unroll
    for (int n = 0; n < 2; ++n) { acc3[n][0]=0.f; acc3[n][1]=0.f; acc3[n][2]=0.f; acc3[n][3]=0.f; }
    #pragma unroll
    for (int k = 0; k < 4; ++k) {
        bf16x8 bfr[2];
        #pragma unroll
        for (int n = 0; n < 2; ++n)
            bfr[n] = *(const bf16x8*)(w3 + ((size_t)f * 32 + n * 16 + p) * 128 + k * 32 + q * 8);
        int row = mrow + p, ch = k * 4 + q;
        bf16x8 afr = *(const bf16x8*)(H2b + (row * 16 + (ch ^ (row & 7))) * 16);
        #pragma unroll
        for (int n = 0; n < 2; ++n)
            acc3[n] = __builtin_amdgcn_mfma_f32_16x16x32_bf16(afr, bfr[n], acc3[n], 0, 0, 0);
    }
    #pragma unroll
    for (int n = 0; n < 2; ++n) {
        float bb = eb3[(size_t)f * 32 + n * 16 + p];
        #pragma unroll
        for (int reg = 0; reg < 4; ++reg) {
            float v = fmaxf(acc3[n][reg] + bb, 0.f);
            int row = r0 + mrow + q * 4 + reg;
            z[(size_t)row * 4096 + f * 32 + n * 16 + p] = v;
        }
    }
}

// ---------------- final dense: out[b,o] = dot(z[b,:], fwt[o,:]) + fb[o] ----------------
__global__ void __launch_bounds__(256) final_k(
    const float* __restrict__ z, const float* __restrict__ fwt,
    const float* __restrict__ fb, float* __restrict__ out)
{
    const int b  = blockIdx.x;
    const int og = blockIdx.y;
    __shared__ float zs[4096];
    for (int i = threadIdx.x; i < 1024; i += 256)
        *(float4*)&zs[i * 4] = *(const float4*)&z[(size_t)b * 4096 + i * 4];
    __syncthreads();

    const int wv = threadIdx.x >> 6, lane = threadIdx.x & 63;
    const int o = og * 4 + wv;
    if (o >= 53) return;
    const float4* wr = (const float4*)&fwt[(size_t)o * 4096];
    float s = 0.f;
    #pragma unroll
    for (int it = 0; it < 16; ++it) {
        float4 zv = *(const float4*)&zs[(it * 64 + lane) * 4];
        float4 w4 = wr[it * 64 + lane];
        s += zv.x * w4.x + zv.y * w4.y + zv.z * w4.z + zv.w * w4.w;
    }
    #pragma unroll
    for (int off = 32; off; off >>= 1) s += __shfl_down(s, off);
    if (lane == 0) out[b * 53 + o] = s + fb[o];
}

extern "C" void kernel_launch(void* const* d_in, const int* in_sizes, int n_in,
                              void* d_out, int out_size, void* d_ws, size_t ws_size,
                              hipStream_t stream)
{
    const float* x   = (const float*)d_in[0];
    const float* cw1 = (const float*)d_in[1];
    const float* cb1 = (const float*)d_in[2];
    const float* cw2 = (const float*)d_in[3];
    const float* cb2 = (const float*)d_in[4];
    const float* cw3 = (const float*)d_in[5];
    const float* cb3 = (const float*)d_in[6];
    const float* Wa  = (const float*)d_in[7];
    const float* ba  = (const float*)d_in[8];
    const float* ew1 = (const float*)d_in[9];
    const float* eb1 = (const float*)d_in[10];
    const float* ew2 = (const float*)d_in[11];
    const float* eb2 = (const float*)d_in[12];
    const float* ew3 = (const float*)d_in[13];
    const float* eb3 = (const float*)d_in[14];
    const float* fw  = (const float*)d_in[15];
    const float* fb  = (const float*)d_in[16];

    // ---- workspace layout: FLOAT offsets (bf16 counts / 2) ----
    float* ws = (float*)d_ws;
    __hip_bfloat16* p1b  = (__hip_bfloat16*)ws;
    __hip_bfloat16* p2b  = (__hip_bfloat16*)(ws + 8388608);
    float* feat = ws + 12582912;
    __hip_bfloat16* wp2  = (__hip_bfloat16*)(ws + 16793600);
    __hip_bfloat16* wp3  = (__hip_bfloat16*)(ws + 16802816);
    __hip_bfloat16* ew1b = (__hip_bfloat16*)(ws + 16839680);
    __hip_bfloat16* ew2b = (__hip_bfloat16*)(ws + 21033984);
    __hip_bfloat16* ew3b = (__hip_bfloat16*)(ws + 23131136);
    float* fwt = ws + 23393280;
    __hip_bfloat16* wp1b = (__hip_bfloat16*)(ws + 23610368);
    float* z   = ws;

    packs_k<<<14016, 256, 0, stream>>>(cw1, cw2, cw3, fw, ew1, ew2, ew3,
                                       wp1b, wp2, wp3, fwt, ew1b, ew2b, ew3b);

    conv1_mfma<<<dim3(16, 1, 128), 512, 0, stream>>>(x, wp1b, cb1, p1b);
    // conv2 now swizzled (mask CH-1 = 3): fixes 64B-pixel-stride bank pile-up on A-reads
    conv_mfma<64, 32, 64, 1, 0><<<dim3(8, 1, 128), 512, 0, stream>>>(p1b, wp2, cb2, p2b, nullptr);
    conv_mfma<32, 64, 128, 1, 1><<<dim3(4, 1, 128), 512, 0, stream>>>(p2b, wp3, cb3, nullptr, feat);
    experts_mfma<<<dim3(128, 2), 256, 0, stream>>>(feat, Wa, ba, ew1b, eb1, ew2b, eb2, ew3b, eb3, z);
    final_k<<<dim3(128, 14), 256, 0, stream>>>(z, fwt, fb, (float*)d_out);
}

// Round 22
// 139.822 us; speedup vs baseline: 1.0134x; 1.0134x over previous
//
#include <hip/hip_runtime.h>
#include <hip/hip_bf16.h>
#include <math.h>

#define NF 128
#define NP 256

typedef __attribute__((ext_vector_type(8))) short bf16x8;
typedef __attribute__((ext_vector_type(4))) short bf16x4;
typedef __attribute__((ext_vector_type(4))) float f32x4;

#define GLOBAL_AS __attribute__((address_space(1)))
#define LDS_AS __attribute__((address_space(3)))

// ---------------- ONE prepack kernel: wp1 | wp2 | wp3 | fwt | tpack(ew1,ew2,ew3) ----------------
__device__ __forceinline__ void tpack_tile(const float* __restrict__ src,
                                           __hip_bfloat16* __restrict__ dst,
                                           int P, int Q, int pt, int qt,
                                           int tid, float (*t)[33])
{
    const int rr = tid >> 5, c = tid & 31;
    #pragma unroll
    for (int i = 0; i < 4; ++i)
        t[rr + i * 8][c] = src[(size_t)(pt * 32 + rr + i * 8) * Q + qt * 32 + c];
    __syncthreads();
    #pragma unroll
    for (int i = 0; i < 4; ++i)
        dst[(size_t)(qt * 32 + rr + i * 8) * P + pt * 32 + c] =
            __float2bfloat16(t[c][rr + i * 8]);
}

__global__ void __launch_bounds__(256) packs_k(
    const float* __restrict__ cw1, const float* __restrict__ cw2,
    const float* __restrict__ cw3, const float* __restrict__ fw,
    const float* __restrict__ ew1, const float* __restrict__ ew2,
    const float* __restrict__ ew3,
    __hip_bfloat16* __restrict__ wp1, __hip_bfloat16* __restrict__ wp2,
    __hip_bfloat16* __restrict__ wp3, float* __restrict__ fwt,
    __hip_bfloat16* __restrict__ ew1b, __hip_bfloat16* __restrict__ ew2b,
    __hip_bfloat16* __restrict__ ew3b)
{
    __shared__ float t[32][33];
    const int bid = blockIdx.x, tid = threadIdx.x;
    if (bid < 8) {
        int i = bid * 256 + tid;
        if (i >= 2048) return;
        int s = i >> 10, co = (i >> 5) & 31, k = i & 31;
        int o = s * 8 + (k >> 2), ch = k & 3;
        float v = 0.f;
        if (o < 9 && ch < 3) v = cw1[(size_t)(co * 3 + ch) * 9 + o];
        wp1[i] = __float2bfloat16(v);
    } else if (bid < 80) {
        int i = (bid - 8) * 256 + tid;
        if (i >= 9 * 64 * 32) return;
        int o = i / 2048, r = i - o * 2048;
        int co = r >> 5, ci = r & 31;
        wp2[i] = __float2bfloat16(cw2[(size_t)(co * 32 + ci) * 9 + o]);
    } else if (bid < 368) {
        int i = (bid - 80) * 256 + tid;
        if (i >= 9 * 128 * 64) return;
        int o = i / 8192, r = i - o * 8192;
        int co = r >> 6, ci = r & 63;
        wp3[i] = __float2bfloat16(cw3[(size_t)(co * 64 + ci) * 9 + o]);
    } else if (bid < 1216) {
        int i = (bid - 368) * 256 + tid;
        if (i >= 53 * 4096) return;
        int o = i >> 12, k = i & 4095;
        fwt[i] = fw[(size_t)k * 53 + o];
    } else if (bid < 9408) {
        int r = bid - 1216;
        int f = r >> 6, tile = r & 63;
        tpack_tile(ew1 + (size_t)f * 65536, ew1b + (size_t)f * 65536,
                   256, 256, tile >> 3, tile & 7, tid, t);
    } else if (bid < 13504) {
        int r = bid - 9408;
        int f = r >> 5, tile = r & 31;
        tpack_tile(ew2 + (size_t)f * 32768, ew2b + (size_t)f * 32768,
                   256, 128, tile >> 2, tile & 3, tid, t);
    } else {
        int r = bid - 13504;
        int f = r >> 2, tile = r & 3;
        tpack_tile(ew3 + (size_t)f * 4096, ew3b + (size_t)f * 4096,
                   128, 32, tile, 0, tid, t);
    }
}

// ---------------- conv1 via MFMA, 512 threads: waves = (row-pair rp, co-half coh) ----------------
__global__ void __launch_bounds__(512, 2) conv1_mfma(
    const float* __restrict__ x,
    const __hip_bfloat16* __restrict__ wp1,
    const float* __restrict__ bias,
    __hip_bfloat16* __restrict__ out)
{
    __shared__ char lds[14 * 130 * 8];
    const int rb  = blockIdx.x * 8;
    const int b   = blockIdx.z;
    const int tid = threadIdx.x;

    #pragma unroll
    for (int t = 0; t < 4; ++t) {
        int u = tid + t * 512;
        if (u < 14 * 130) {
            int px = u % 130, row = u / 130;
            int gy = rb + row - 1, gx = px - 1;
            unsigned short hv[4] = {0, 0, 0, 0};
            if (gy >= 0 && gy < 128 && gx >= 0 && gx < 128) {
                size_t base = (((size_t)b * 3) * 128 + gy) * 128 + gx;
                __hip_bfloat16 h0 = __float2bfloat16(x[base]);
                __hip_bfloat16 h1 = __float2bfloat16(x[base + 16384]);
                __hip_bfloat16 h2 = __float2bfloat16(x[base + 32768]);
                __builtin_memcpy(&hv[0], &h0, 2);
                __builtin_memcpy(&hv[1], &h1, 2);
                __builtin_memcpy(&hv[2], &h2, 2);
            }
            *(int2*)(lds + u * 8) = *(const int2*)hv;
        }
    }
    __syncthreads();

    const int lane = threadIdx.x & 63, p = lane & 15, q = lane >> 4;
    const int w = threadIdx.x >> 6;
    const int rp = w & 3, coh = w >> 2;

    f32x4 acc[16];
    #pragma unroll
    for (int m = 0; m < 16; ++m) {
        acc[m][0] = 0.f; acc[m][1] = 0.f; acc[m][2] = 0.f; acc[m][3] = 0.f;
    }

    #pragma unroll
    for (int s = 0; s < 2; ++s) {
        bf16x8 bfr = *(const bf16x8*)(wp1 + (size_t)(s * 32 + coh * 16 + p) * 32 + q * 8);
        const int o0 = s * 8 + q * 2, o1 = o0 + 1;
        const int dy0 = o0 / 3, dx0 = o0 - 3 * dy0;
        const int dy1 = o1 / 3, dx1 = o1 - 3 * dy1;
        #pragma unroll
        for (int m = 0; m < 16; ++m) {
            const int mr = m >> 3, mx = m & 7;
            const int r0 = (2 * rp + mr + dy0) * 130 + mx * 16 + p + dx0;
            const int r1 = (2 * rp + mr + dy1) * 130 + mx * 16 + p + dx1;
            bf16x4 lo = *(const bf16x4*)(lds + r0 * 8);
            bf16x4 hi = *(const bf16x4*)(lds + r1 * 8);
            bf16x8 afr = __builtin_shufflevector(lo, hi, 0, 1, 2, 3, 4, 5, 6, 7);
            acc[m] = __builtin_amdgcn_mfma_f32_16x16x32_bf16(afr, bfr, acc[m], 0, 0, 0);
        }
    }

    const int prow = (rb >> 1) + rp;
    const float bv = bias[coh * 16 + p];
    #pragma unroll
    for (int mx = 0; mx < 8; ++mx) {
        f32x4 lo = acc[mx], hi = acc[8 + mx];
        float v0 = fmaxf(fmaxf(fmaxf(lo[0], lo[1]), fmaxf(hi[0], hi[1])) + bv, 0.f);
        float v1 = fmaxf(fmaxf(fmaxf(lo[2], lo[3]), fmaxf(hi[2], hi[3])) + bv, 0.f);
        int px = mx * 8 + q * 2;
        size_t base = ((size_t)(b * 64 + prow) * 64 + px) * 32 + coh * 16 + p;
        out[base]      = __float2bfloat16(v0);
        out[base + 32] = __float2bfloat16(v1);
    }
}

// ---------------- MFMA conv3x3 + ReLU + maxpool2 (FROZEN best form: 512 thr, 8 waves) ----------------
template<int W, int CIN, int COUT, int SWZ, int OUTF>
__global__ void __launch_bounds__(512, 2) conv_mfma(
    const __hip_bfloat16* __restrict__ in,
    const __hip_bfloat16* __restrict__ wp,
    const float* __restrict__ bias,
    __hip_bfloat16* __restrict__ outb,
    float* __restrict__ outf)
{
    constexpr int XW  = W / 16;
    constexpr int AF  = 2 * XW;
    constexpr int BF  = COUT / 32;
    constexpr int CH  = CIN / 8;
    constexpr int KH  = CIN / 32;
    constexpr int NSTEP = 9 * KH;
    constexpr int PXW = W + 2;
    constexpr int UNITS  = 10 * PXW * CH;
    constexpr int NIT    = (UNITS + 511) / 512;
    constexpr int STAGEB = UNITS * 16;
    constexpr int OUTLDS = OUTF ? (COUT * 68 * 4) : 0;
    constexpr int LDSB   = STAGEB > OUTLDS ? STAGEB : OUTLDS;

    __shared__ int4 ldsv[(LDSB + 15) / 16];
    char* ldsc = (char*)ldsv;

    const int rb  = blockIdx.x * 8;
    const int b   = blockIdx.z;
    const int tid = threadIdx.x;
    const int w = tid >> 6, lane = tid & 63, p = lane & 15, q = lane >> 4;
    const int rp = w & 3, coh = w >> 2;
    const int cb = coh * (COUT / 2);

    #pragma unroll
    for (int t = 0; t < NIT; ++t) {
        int u = tid + t * 512;
        if (u < UNITS) {
            int ch = u % CH; int pl = u / CH;
            int xx = pl % PXW; int row = pl / PXW;
            int gy = rb + row - 1, gx = xx - 1;
            if (gy >= 0 && gy < W && gx >= 0 && gx < W) {
                int ch_src = SWZ ? (ch ^ (pl & 7)) : ch;
                const __hip_bfloat16* gp = in + ((size_t)(b * W + gy) * W + gx) * CIN + ch_src * 8;
                char* lb = ldsc + (size_t)(t * 512 + (tid & ~63)) * 16;
                __builtin_amdgcn_global_load_lds(
                    (const GLOBAL_AS void*)gp, (LDS_AS void*)lb, 16, 0, 0);
            } else {
                *(int4*)(ldsc + (size_t)u * 16) = make_int4(0, 0, 0, 0);
            }
        }
    }

    bf16x8 bcur[BF], bnxt[BF];
    #pragma unroll
    for (int n = 0; n < BF; ++n)
        bcur[n] = *(const bf16x8*)(wp + (size_t)(cb + n * 16 + p) * CIN + q * 8);

    __syncthreads();

    f32x4 acc[AF][BF];
    #pragma unroll
    for (int m = 0; m < AF; ++m)
        #pragma unroll
        for (int n = 0; n < BF; ++n) {
            acc[m][n][0] = 0.f; acc[m][n][1] = 0.f;
            acc[m][n][2] = 0.f; acc[m][n][3] = 0.f;
        }

    float bv[BF];
    #pragma unroll
    for (int n = 0; n < BF; ++n) bv[n] = bias[cb + n * 16 + p];

    #pragma unroll 1
    for (int s = 0; s < NSTEP; ++s) {
        const int o  = (KH == 1) ? s : (s >> 1);
        const int h  = (KH == 1) ? 0 : (s & 1);
        const int ky = o / 3, kx = o - 3 * (o / 3);

        if (s + 1 < NSTEP) {
            const int o2 = (KH == 1) ? (s + 1) : ((s + 1) >> 1);
            const int h2 = (KH == 1) ? 0 : ((s + 1) & 1);
            #pragma unroll
            for (int n = 0; n < BF; ++n)
                bnxt[n] = *(const bf16x8*)(wp + (size_t)(o2 * COUT + cb + n * 16 + p) * CIN + h2 * 32 + q * 8);
        }

        bf16x8 afr[AF];
        #pragma unroll
        for (int m = 0; m < AF; ++m) {
            const int mr = m / XW, mx = m % XW;
            const int pix = (2 * rp + mr + ky) * PXW + mx * 16 + kx + p;
            const int ch = h * 4 + q;
            const int slot = SWZ ? (pix * CH + (ch ^ (pix & 7))) : (pix * CH + ch);
            afr[m] = *(const bf16x8*)(ldsc + slot * 16);
        }
        #pragma unroll
        for (int m = 0; m < AF; ++m)
            #pragma unroll
            for (int n = 0; n < BF; ++n)
                acc[m][n] = __builtin_amdgcn_mfma_f32_16x16x32_bf16(afr[m], bcur[n], acc[m][n], 0, 0, 0);

        #pragma unroll
        for (int n = 0; n < BF; ++n) bcur[n] = bnxt[n];
    }

    const int prow = (rb >> 1) + rp;
    if constexpr (OUTF == 0) {
        #pragma unroll
        for (int mx = 0; mx < XW; ++mx)
            #pragma unroll
            for (int n = 0; n < BF; ++n) {
                f32x4 lo = acc[mx][n], hi = acc[XW + mx][n];
                float v0 = fmaxf(fmaxf(fmaxf(lo[0], lo[1]), fmaxf(hi[0], hi[1])) + bv[n], 0.f);
                float v1 = fmaxf(fmaxf(fmaxf(lo[2], lo[3]), fmaxf(hi[2], hi[3])) + bv[n], 0.f);
                int px = mx * 8 + q * 2;
                size_t base = ((size_t)(b * (W / 2) + prow) * (W / 2) + px) * COUT + cb + n * 16 + p;
                outb[base]        = __float2bfloat16(v0);
                outb[base + COUT] = __float2bfloat16(v1);
            }
    } else {
        __syncthreads();
        float* fl = (float*)ldsc;
        #pragma unroll
        for (int mx = 0; mx < XW; ++mx)
            #pragma unroll
            for (int n = 0; n < BF; ++n) {
                f32x4 lo = acc[mx][n], hi = acc[XW + mx][n];
                float v0 = fmaxf(fmaxf(fmaxf(lo[0], lo[1]), fmaxf(hi[0], hi[1])) + bv[n], 0.f);
                float v1 = fmaxf(fmaxf(fmaxf(lo[2], lo[3]), fmaxf(hi[2], hi[3])) + bv[n], 0.f);
                int px = mx * 8 + q * 2;
                fl[(cb + n * 16 + p) * 68 + rp * 16 + px]     = v0;
                fl[(cb + n * 16 + p) * 68 + rp * 16 + px + 1] = v1;
            }
        __syncthreads();
        for (int i = tid; i < COUT * 16; i += 512) {
            int c = i >> 4, j4 = i & 15;
            float4 vv = *(const float4*)&fl[c * 68 + j4 * 4];
            *(float4*)(outf + (size_t)(b * COUT + c) * 256 + (rb >> 1) * 16 + j4 * 4) = vv;
        }
    }
}

// ---------------- experts via MFMA, 64-row blocks, fused attention (in-register) ----------------
__global__ void __launch_bounds__(256, 2) experts_mfma(
    const float* __restrict__ feat, const float* __restrict__ Wa,
    const float* __restrict__ ba,
    const __hip_bfloat16* __restrict__ w1, const float* __restrict__ eb1,
    const __hip_bfloat16* __restrict__ w2, const float* __restrict__ eb2,
    const __hip_bfloat16* __restrict__ w3, const float* __restrict__ eb3,
    float* __restrict__ z)
{
    const int f  = blockIdx.x;
    const int r0 = blockIdx.y * 64;
    const int tid = threadIdx.x;

    __shared__ __attribute__((aligned(16))) char lds[65536];
    char* Xb  = lds;
    char* H1b = lds + 32768;
    char* H2b = lds;

    #pragma unroll
    for (int t = 0; t < 8; ++t) {
        int u = tid + t * 256;
        int row = u >> 5, ch = u & 31;
        int b = r0 + row;
        const float* src = feat + ((size_t)b * NF + f) * NP + ch * 8;
        float4 v0 = *(const float4*)src;
        float4 v1 = *(const float4*)(src + 4);
        unsigned short hv[8];
        float vv[8] = {v0.x, v0.y, v0.z, v0.w, v1.x, v1.y, v1.z, v1.w};
        #pragma unroll
        for (int j = 0; j < 8; ++j) {
            __hip_bfloat16 hb = __float2bfloat16(vv[j]);
            __builtin_memcpy(&hv[j], &hb, 2);
        }
        int slot = row * 32 + (ch ^ (row & 7));
        *(int4*)(Xb + slot * 16) = *(const int4*)hv;
    }

    const int wv = tid >> 6, lane = tid & 63, p = lane & 15, q = lane >> 4;
    const int mrow = wv * 16;

    float att_val;
    {
        int rl = lane >> 2, sub = lane & 3;
        const float* fr = feat + ((size_t)(r0 + mrow + rl) * NF + f) * NP + sub * 64;
        const float* wr = Wa + (size_t)f * NP + sub * 64;
        float s = 0.f;
        #pragma unroll
        for (int j = 0; j < 64; j += 4) {
            float4 a  = *(const float4*)(fr + j);
            float4 w4 = *(const float4*)(wr + j);
            s += a.x * w4.x + a.y * w4.y + a.z * w4.z + a.w * w4.w;
        }
        s += __shfl_xor(s, 1);
        s += __shfl_xor(s, 2);
        att_val = 1.f / (1.f + expf(-(s + ba[f])));
    }
    __syncthreads();

    f32x4 acc1[16];
    #pragma unroll
    for (int n = 0; n < 16; ++n) { acc1[n][0]=0.f; acc1[n][1]=0.f; acc1[n][2]=0.f; acc1[n][3]=0.f; }
    #pragma unroll
    for (int k = 0; k < 8; ++k) {
        bf16x8 bfr[16];
        #pragma unroll
        for (int n = 0; n < 16; ++n)
            bfr[n] = *(const bf16x8*)(w1 + ((size_t)f * 256 + n * 16 + p) * 256 + k * 32 + q * 8);
        int row = mrow + p, ch = k * 4 + q;
        bf16x8 afr = *(const bf16x8*)(Xb + (row * 32 + (ch ^ (row & 7))) * 16);
        #pragma unroll
        for (int n = 0; n < 16; ++n)
            acc1[n] = __builtin_amdgcn_mfma_f32_16x16x32_bf16(afr, bfr[n], acc1[n], 0, 0, 0);
    }
    #pragma unroll
    for (int n = 0; n < 16; ++n) {
        int col = n * 16 + p;
        float bb = eb1[(size_t)f * 256 + col];
        #pragma unroll
        for (int reg = 0; reg < 4; ++reg) {
            int rowl = q * 4 + reg;
            float av = __shfl(att_val, rowl << 2);
            float v = fmaxf(av * acc1[n][reg] + bb, 0.f);
            int row = mrow + rowl;
            int slot = row * 32 + ((col >> 3) ^ (row & 7));
            *(__hip_bfloat16*)(H1b + slot * 16 + (col & 7) * 2) = __float2bfloat16(v);
        }
    }
    __syncthreads();

    f32x4 acc2[8];
    #pragma unroll
    for (int n = 0; n < 8; ++n) { acc2[n][0]=0.f; acc2[n][1]=0.f; acc2[n][2]=0.f; acc2[n][3]=0.f; }
    #pragma unroll
    for (int k = 0; k < 8; ++k) {
        bf16x8 bfr[8];
        #pragma unroll
        for (int n = 0; n < 8; ++n)
            bfr[n] = *(const bf16x8*)(w2 + ((size_t)f * 128 + n * 16 + p) * 256 + k * 32 + q * 8);
        int row = mrow + p, ch = k * 4 + q;
        bf16x8 afr = *(const bf16x8*)(H1b + (row * 32 + (ch ^ (row & 7))) * 16);
        #pragma unroll
        for (int n = 0; n < 8; ++n)
            acc2[n] = __builtin_amdgcn_mfma_f32_16x16x32_bf16(afr, bfr[n], acc2[n], 0, 0, 0);
    }
    #pragma unroll
    for (int n = 0; n < 8; ++n) {
        int col = n * 16 + p;
        float bb = eb2[(size_t)f * 128 + col];
        #pragma unroll
        for (int reg = 0; reg < 4; ++reg) {
            float v = fmaxf(acc2[n][reg] + bb, 0.f);
            int row = mrow + q * 4 + reg;
            int slot = row * 16 + ((col >> 3) ^ (row & 7));
            *(__hip_bfloat16*)(H2b + slot * 16 + (col & 7) * 2) = __float2bfloat16(v);
        }
    }
    __syncthreads();

    f32x4 acc3[2];
    #pragma unroll
    for (int n = 0; n < 2; ++n) { acc3[n][0]=0.f; acc3[n][1]=0.f; acc3[n][2]=0.f; acc3[n][3]=0.f; }
    #pragma unroll
    for (int k = 0; k < 4; ++k) {
        bf16x8 bfr[2];
        #pragma unroll
        for (int n = 0; n < 2; ++n)
            bfr[n] = *(const bf16x8*)(w3 + ((size_t)f * 32 + n * 16 + p) * 128 + k * 32 + q * 8);
        int row = mrow + p, ch = k * 4 + q;
        bf16x8 afr = *(const bf16x8*)(H2b + (row * 16 + (ch ^ (row & 7))) * 16);
        #pragma unroll
        for (int n = 0; n < 2; ++n)
            acc3[n] = __builtin_amdgcn_mfma_f32_16x16x32_bf16(afr, bfr[n], acc3[n], 0, 0, 0);
    }
    #pragma unroll
    for (int n = 0; n < 2; ++n) {
        float bb = eb3[(size_t)f * 32 + n * 16 + p];
        #pragma unroll
        for (int reg = 0; reg < 4; ++reg) {
            float v = fmaxf(acc3[n][reg] + bb, 0.f);
            int row = r0 + mrow + q * 4 + reg;
            z[(size_t)row * 4096 + f * 32 + n * 16 + p] = v;
        }
    }
}

// ---------------- final dense: out[b,o] = dot(z[b,:], fwt[o,:]) + fb[o] ----------------
__global__ void __launch_bounds__(256) final_k(
    const float* __restrict__ z, const float* __restrict__ fwt,
    const float* __restrict__ fb, float* __restrict__ out)
{
    const int b  = blockIdx.x;
    const int og = blockIdx.y;
    __shared__ float zs[4096];
    for (int i = threadIdx.x; i < 1024; i += 256)
        *(float4*)&zs[i * 4] = *(const float4*)&z[(size_t)b * 4096 + i * 4];
    __syncthreads();

    const int wv = threadIdx.x >> 6, lane = threadIdx.x & 63;
    const int o = og * 4 + wv;
    if (o >= 53) return;
    const float4* wr = (const float4*)&fwt[(size_t)o * 4096];
    float s = 0.f;
    #pragma unroll
    for (int it = 0; it < 16; ++it) {
        float4 zv = *(const float4*)&zs[(it * 64 + lane) * 4];
        float4 w4 = wr[it * 64 + lane];
        s += zv.x * w4.x + zv.y * w4.y + zv.z * w4.z + zv.w * w4.w;
    }
    #pragma unroll
    for (int off = 32; off; off >>= 1) s += __shfl_down(s, off);
    if (lane == 0) out[b * 53 + o] = s + fb[o];
}

extern "C" void kernel_launch(void* const* d_in, const int* in_sizes, int n_in,
                              void* d_out, int out_size, void* d_ws, size_t ws_size,
                              hipStream_t stream)
{
    const float* x   = (const float*)d_in[0];
    const float* cw1 = (const float*)d_in[1];
    const float* cb1 = (const float*)d_in[2];
    const float* cw2 = (const float*)d_in[3];
    const float* cb2 = (const float*)d_in[4];
    const float* cw3 = (const float*)d_in[5];
    const float* cb3 = (const float*)d_in[6];
    const float* Wa  = (const float*)d_in[7];
    const float* ba  = (const float*)d_in[8];
    const float* ew1 = (const float*)d_in[9];
    const float* eb1 = (const float*)d_in[10];
    const float* ew2 = (const float*)d_in[11];
    const float* eb2 = (const float*)d_in[12];
    const float* ew3 = (const float*)d_in[13];
    const float* eb3 = (const float*)d_in[14];
    const float* fw  = (const float*)d_in[15];
    const float* fb  = (const float*)d_in[16];

    // ---- workspace layout: FLOAT offsets (bf16 counts / 2) ----
    float* ws = (float*)d_ws;
    __hip_bfloat16* p1b  = (__hip_bfloat16*)ws;
    __hip_bfloat16* p2b  = (__hip_bfloat16*)(ws + 8388608);
    float* feat = ws + 12582912;
    __hip_bfloat16* wp2  = (__hip_bfloat16*)(ws + 16793600);
    __hip_bfloat16* wp3  = (__hip_bfloat16*)(ws + 16802816);
    __hip_bfloat16* ew1b = (__hip_bfloat16*)(ws + 16839680);
    __hip_bfloat16* ew2b = (__hip_bfloat16*)(ws + 21033984);
    __hip_bfloat16* ew3b = (__hip_bfloat16*)(ws + 23131136);
    float* fwt = ws + 23393280;
    __hip_bfloat16* wp1b = (__hip_bfloat16*)(ws + 23610368);
    float* z   = ws;

    packs_k<<<14016, 256, 0, stream>>>(cw1, cw2, cw3, fw, ew1, ew2, ew3,
                                       wp1b, wp2, wp3, fwt, ew1b, ew2b, ew3b);

    conv1_mfma<<<dim3(16, 1, 128), 512, 0, stream>>>(x, wp1b, cb1, p1b);
    conv_mfma<64, 32, 64, 0, 0><<<dim3(8, 1, 128), 512, 0, stream>>>(p1b, wp2, cb2, p2b, nullptr);
    conv_mfma<32, 64, 128, 1, 1><<<dim3(4, 1, 128), 512, 0, stream>>>(p2b, wp3, cb3, nullptr, feat);
    experts_mfma<<<dim3(128, 2), 256, 0, stream>>>(feat, Wa, ba, ew1b, eb1, ew2b, eb2, ew3b, eb3, z);
    final_k<<<dim3(128, 14), 256, 0, stream>>>(z, fwt, fb, (float*)d_out);
}